// Round 1
// baseline (107.984 us; speedup 1.0000x reference)
//
#include <hip/hip_runtime.h>
#include <stdint.h>

#define DIM 512
#define NHEADS 8
#define HDIM 64
#define NBINS 961
#define BATCH 64
#define SEQ 256
#define NTOK (BATCH*SEQ)            // 16384
#define BHND (BATCH*NHEADS*SEQ*HDIM) // 8388608 elements per q/k/v tensor

using bf16x8 = __attribute__((ext_vector_type(8))) short;
using f32x4  = __attribute__((ext_vector_type(4))) float;

__device__ __forceinline__ unsigned short f2bf(float f) {
  unsigned u = __float_as_uint(f);
  u += 0x7FFF + ((u >> 16) & 1);   // round-to-nearest-even
  return (unsigned short)(u >> 16);
}

__device__ __forceinline__ void async16(const void* g, void* lds) {
  __builtin_amdgcn_global_load_lds(
      (const __attribute__((address_space(1))) unsigned int*)g,
      (__attribute__((address_space(3))) unsigned int*)lds,
      16, 0, 0);
}

// ---------------- prep kernels ----------------

__global__ void cast_kernel(const float* __restrict__ in,
                            unsigned short* __restrict__ out, int n4) {
  int i = blockIdx.x * 256 + threadIdx.x;
  if (i >= n4) return;
  float4 f = reinterpret_cast<const float4*>(in)[i];
  ushort4 o;
  o.x = f2bf(f.x); o.y = f2bf(f.y); o.z = f2bf(f.z); o.w = f2bf(f.w);
  reinterpret_cast<ushort4*>(out)[i] = o;
}

__global__ void bias_kernel(const int* __restrict__ idx,
                            const float* __restrict__ rpb,
                            float* __restrict__ bf) {
  int i = blockIdx.x * 256 + threadIdx.x;   // [0, 8*65536)
  if (i >= NHEADS * SEQ * SEQ) return;
  int h = i >> 16;
  int r = i & 65535;
  bf[i] = rpb[h * NBINS + idx[r]];
}

// ---------------- GEMM: C = A(M x 512) * B^T(N x 512) + bias ----------------
// EPI 0: scatter into q/k/v (B,H,N,D) bf16.  EPI 1: fp32 out row-major + bias.

template<int EPI>
__global__ __launch_bounds__(256) void gemm_bt(
    const unsigned short* __restrict__ A,
    const unsigned short* __restrict__ Bw,
    const float* __restrict__ bias,
    void* __restrict__ outp) {
  __shared__ char gsm[16384];
  char* As = gsm;
  char* Bs = gsm + 8192;
  const int t = threadIdx.x;
  const int lane = t & 63;
  const int l15 = lane & 15, lg = lane >> 4;
  const int m0 = blockIdx.x * 128, n0 = blockIdx.y * 128;
  const int wv = t >> 6;
  const int wm = wv & 1, wn = wv >> 1;

  f32x4 acc[4][4];
  const f32x4 fz = {0.f, 0.f, 0.f, 0.f};
#pragma unroll
  for (int a = 0; a < 4; ++a)
#pragma unroll
    for (int b = 0; b < 4; ++b) acc[a][b] = fz;

  for (int kk = 0; kk < 512; kk += 32) {
#pragma unroll
    for (int i = 0; i < 2; ++i) {
      int c = t + i * 256;            // 16B chunk id in [0,512)
      const unsigned short* ga = A + (size_t)(m0 + (c >> 2)) * 512 + kk + (c & 3) * 8;
      async16(ga, As + ((size_t)i * 256 + (size_t)((t >> 6) << 6)) * 16);
      const unsigned short* gb = Bw + (size_t)(n0 + (c >> 2)) * 512 + kk + (c & 3) * 8;
      async16(gb, Bs + ((size_t)i * 256 + (size_t)((t >> 6) << 6)) * 16);
    }
    __syncthreads();
    bf16x8 af[4], bfr[4];
#pragma unroll
    for (int x = 0; x < 4; ++x) {
      af[x]  = *(const bf16x8*)(As + ((wm * 64 + x * 16 + l15) * 32 + lg * 8) * 2);
      bfr[x] = *(const bf16x8*)(Bs + ((wn * 64 + x * 16 + l15) * 32 + lg * 8) * 2);
    }
#pragma unroll
    for (int mi = 0; mi < 4; ++mi)
#pragma unroll
      for (int ni = 0; ni < 4; ++ni)
        acc[mi][ni] = __builtin_amdgcn_mfma_f32_16x16x32_bf16(af[mi], bfr[ni], acc[mi][ni], 0, 0, 0);
    __syncthreads();
  }

#pragma unroll
  for (int mi = 0; mi < 4; ++mi)
#pragma unroll
    for (int ni = 0; ni < 4; ++ni)
#pragma unroll
      for (int r = 0; r < 4; ++r) {
        int row = m0 + wm * 64 + mi * 16 + lg * 4 + r;
        int col = n0 + wn * 64 + ni * 16 + l15;
        float v = acc[mi][ni][r] + bias[col];
        if (EPI == 0) {
          int which = col >> 9, hd = col & 511;
          int b = row >> 8, n = row & 255;
          ((unsigned short*)outp)[(size_t)which * BHND +
              (((size_t)(b * NHEADS + (hd >> 6)) * SEQ + n) * HDIM) + (hd & 63)] = f2bf(v);
        } else {
          ((float*)outp)[(size_t)row * 512 + col] = v;
        }
      }
}

// ---------------- fused attention: one block per (b,h) ----------------

__global__ __launch_bounds__(512, 2) void attn_kernel(
    const unsigned short* __restrict__ qb,
    const unsigned short* __restrict__ kb,
    const unsigned short* __restrict__ vb,
    const float* __restrict__ biasf,
    unsigned short* __restrict__ aout) {
  extern __shared__ char smem[];
  char* k_s = smem;               // 32 KB: [256 keys][64 d] bf16, XOR-swizzled rows
  char* v_s = smem + 32768;       // 32 KB: vT [64 d][256 keys] bf16, XOR-swizzled rows
  const int t = threadIdx.x, lane = t & 63, w = t >> 6;
  const int l15 = lane & 15, lg = lane >> 4;
  char* P_s = smem + 65536 + w * 4096;  // per-wave [32 rows][64 keys] bf16, swizzled
  const int bh = blockIdx.x;
  const int h = bh & 7;
  const int b = bh >> 3;
  const size_t base = (size_t)bh * (SEQ * HDIM);

  // stage K (swizzled row-major)
#pragma unroll
  for (int i = 0; i < 4; ++i) {
    int c = i * 512 + t;            // 16B chunk, 2048 total
    int row = c >> 3, sl = c & 7;
    bf16x8 val = *(const bf16x8*)(kb + base + (size_t)c * 8);
    *(bf16x8*)(k_s + row * 128 + ((sl * 16) ^ ((row & 7) << 4))) = val;
  }
  // stage V transposed (vT[d][key], swizzled)
#pragma unroll
  for (int i = 0; i < 4; ++i) {
    int c = i * 512 + t;
    int key = c >> 3, d0 = (c & 7) * 8;
    bf16x8 val = *(const bf16x8*)(vb + base + (size_t)c * 8);
#pragma unroll
    for (int j = 0; j < 8; ++j) {
      int d = d0 + j;
      *(short*)(v_s + d * 512 + ((key * 2) ^ ((d & 7) << 4))) = val[j];
    }
  }
  // q fragments straight from global (L2-resident)
  bf16x8 qa[2][2];
#pragma unroll
  for (int rf = 0; rf < 2; ++rf)
#pragma unroll
    for (int ks = 0; ks < 2; ++ks)
      qa[rf][ks] = *(const bf16x8*)(qb + base + (size_t)(w * 32 + rf * 16 + l15) * 64 + ks * 32 + lg * 8);
  __syncthreads();

  // scores: S = q . k^T   (wave owns 32 query rows x 256 keys)
  f32x4 accs[2][16];
  const f32x4 fz = {0.f, 0.f, 0.f, 0.f};
#pragma unroll
  for (int a = 0; a < 2; ++a)
#pragma unroll
    for (int c = 0; c < 16; ++c) accs[a][c] = fz;
#pragma unroll
  for (int cf = 0; cf < 16; ++cf) {
    int key = cf * 16 + l15;
#pragma unroll
    for (int ks = 0; ks < 2; ++ks) {
      bf16x8 kf = *(const bf16x8*)(k_s + key * 128 + ((lg * 16 + ks * 64) ^ ((key & 7) << 4)));
      accs[0][cf] = __builtin_amdgcn_mfma_f32_16x16x32_bf16(qa[0][ks], kf, accs[0][cf], 0, 0, 0);
      accs[1][cf] = __builtin_amdgcn_mfma_f32_16x16x32_bf16(qa[1][ks], kf, accs[1][cf], 0, 0, 0);
    }
  }

  // scale + rel-pos bias
  const float* bh_ptr = biasf + h * 65536;
#pragma unroll
  for (int rf = 0; rf < 2; ++rf)
#pragma unroll
    for (int r = 0; r < 4; ++r) {
      int n = w * 32 + rf * 16 + lg * 4 + r;
      const float* bp = bh_ptr + n * 256 + l15;
#pragma unroll
      for (int cf = 0; cf < 16; ++cf)
        accs[rf][cf][r] = accs[rf][cf][r] * 0.125f + bp[cf * 16];
    }

  // softmax across 256 keys (16 in-lane x 16 lanes)
  float pinv[2][4];
#pragma unroll
  for (int rf = 0; rf < 2; ++rf)
#pragma unroll
    for (int r = 0; r < 4; ++r) {
      float m = -1e30f;
#pragma unroll
      for (int cf = 0; cf < 16; ++cf) m = fmaxf(m, accs[rf][cf][r]);
#pragma unroll
      for (int off = 1; off < 16; off <<= 1) m = fmaxf(m, __shfl_xor(m, off, 64));
      float s = 0.f;
#pragma unroll
      for (int cf = 0; cf < 16; ++cf) {
        float p = __expf(accs[rf][cf][r] - m);
        accs[rf][cf][r] = p;
        s += p;
      }
#pragma unroll
      for (int off = 1; off < 16; off <<= 1) s += __shfl_xor(s, off, 64);
      pinv[rf][r] = 1.0f / s;
    }

  // PV: out = P . V, P staged per-wave through LDS in 64-key chunks
  f32x4 acco[2][4];
#pragma unroll
  for (int a = 0; a < 2; ++a)
#pragma unroll
    for (int c2 = 0; c2 < 4; ++c2) acco[a][c2] = fz;

  for (int ch = 0; ch < 4; ++ch) {
#pragma unroll
    for (int rf = 0; rf < 2; ++rf)
#pragma unroll
      for (int cl = 0; cl < 4; ++cl)
#pragma unroll
        for (int r = 0; r < 4; ++r) {
          int rowl = rf * 16 + lg * 4 + r;
          int ml = cl * 16 + l15;
          float p = accs[rf][ch * 4 + cl][r] * pinv[rf][r];
          *(short*)(P_s + rowl * 128 + ((ml * 2) ^ ((rowl & 7) << 4))) = (short)f2bf(p);
        }
#pragma unroll
    for (int ks = 0; ks < 2; ++ks) {
      bf16x8 pa[2];
#pragma unroll
      for (int rf = 0; rf < 2; ++rf) {
        int row = rf * 16 + l15;
        pa[rf] = *(const bf16x8*)(P_s + row * 128 + ((lg * 16 + ks * 64) ^ ((row & 7) << 4)));
      }
      int keyb = (ch * 64 + ks * 32 + lg * 8) * 2;
#pragma unroll
      for (int df = 0; df < 4; ++df) {
        int d = df * 16 + l15;
        bf16x8 vf = *(const bf16x8*)(v_s + d * 512 + (keyb ^ ((d & 7) << 4)));
        acco[0][df] = __builtin_amdgcn_mfma_f32_16x16x32_bf16(pa[0], vf, acco[0][df], 0, 0, 0);
        acco[1][df] = __builtin_amdgcn_mfma_f32_16x16x32_bf16(pa[1], vf, acco[1][df], 0, 0, 0);
      }
    }
  }

  // write attn output in (b, n, h*64+d) bf16
#pragma unroll
  for (int rf = 0; rf < 2; ++rf)
#pragma unroll
    for (int df = 0; df < 4; ++df)
#pragma unroll
      for (int r = 0; r < 4; ++r) {
        int n = w * 32 + rf * 16 + lg * 4 + r;
        int d = df * 16 + l15;
        aout[((size_t)(b * SEQ + n)) * DIM + h * HDIM + d] = f2bf(acco[rf][df][r]);
      }
}

// ---------------- launch ----------------

extern "C" void kernel_launch(void* const* d_in, const int* in_sizes, int n_in,
                              void* d_out, int out_size, void* d_ws, size_t ws_size,
                              hipStream_t stream) {
  const float* x      = (const float*)d_in[0];
  const int*   rpi    = (const int*)d_in[1];
  const float* qkv_w  = (const float*)d_in[2];
  const float* qkv_b  = (const float*)d_in[3];
  const float* proj_w = (const float*)d_in[4];
  const float* proj_b = (const float*)d_in[5];
  const float* rpb    = (const float*)d_in[6];

  char* ws = (char*)d_ws;
  unsigned short* xb    = (unsigned short*)ws;                  // 16,777,216 B
  unsigned short* wqkv  = (unsigned short*)(ws + 16777216);     //  1,572,864 B
  unsigned short* wproj = (unsigned short*)(ws + 18350080);     //    524,288 B
  float*          biasf = (float*)         (ws + 18874368);     //  2,097,152 B
  unsigned short* qkvb  = (unsigned short*)(ws + 20971520);     // 50,331,648 B (q,k,v)
  unsigned short* aoutb = (unsigned short*)(ws + 71303168);     // 16,777,216 B
  // total ws use: 88,080,384 B

  cast_kernel<<<8192, 256, 0, stream>>>(x, xb, 2097152);
  cast_kernel<<<768, 256, 0, stream>>>(qkv_w, wqkv, 196608);
  cast_kernel<<<256, 256, 0, stream>>>(proj_w, wproj, 65536);
  bias_kernel<<<2048, 256, 0, stream>>>(rpi, rpb, biasf);

  dim3 g1(128, 12);
  gemm_bt<0><<<g1, 256, 0, stream>>>(xb, wqkv, qkv_b, (void*)qkvb);

  attn_kernel<<<512, 512, 98304, stream>>>(qkvb, qkvb + BHND, qkvb + 2 * (size_t)BHND,
                                           biasf, aoutb);

  dim3 g2(128, 4);
  gemm_bt<1><<<g2, 256, 0, stream>>>(aoutb, wproj, proj_b, d_out);
}

// Round 2
// 102.127 us; speedup vs baseline: 1.0573x; 1.0573x over previous
//
#include <hip/hip_runtime.h>
#include <stdint.h>

#define DIM 512
#define NHEADS 8
#define HDIM 64
#define NBINS 961
#define BATCH 64
#define SEQ 256
#define NTOK (BATCH*SEQ)            // 16384
#define BHND (BATCH*NHEADS*SEQ*HDIM) // 8388608 elements per q/k/v tensor

using bf16x8 = __attribute__((ext_vector_type(8))) short;
using f32x4  = __attribute__((ext_vector_type(4))) float;

__device__ __forceinline__ unsigned short f2bf(float f) {
  unsigned u = __float_as_uint(f);
  u += 0x7FFF + ((u >> 16) & 1);   // round-to-nearest-even
  return (unsigned short)(u >> 16);
}

__device__ __forceinline__ void async16(const void* g, void* lds) {
  __builtin_amdgcn_global_load_lds(
      (const __attribute__((address_space(1))) unsigned int*)g,
      (__attribute__((address_space(3))) unsigned int*)lds,
      16, 0, 0);
}

// ---------------- prep kernels ----------------

__global__ void cast_kernel(const float* __restrict__ in,
                            unsigned short* __restrict__ out, int n4) {
  int i = blockIdx.x * 256 + threadIdx.x;
  if (i >= n4) return;
  float4 f = reinterpret_cast<const float4*>(in)[i];
  ushort4 o;
  o.x = f2bf(f.x); o.y = f2bf(f.y); o.z = f2bf(f.z); o.w = f2bf(f.w);
  reinterpret_cast<ushort4*>(out)[i] = o;
}

__global__ void bias_kernel(const int* __restrict__ idx,
                            const float* __restrict__ rpb,
                            float* __restrict__ bf) {
  int i = blockIdx.x * 256 + threadIdx.x;   // [0, 8*65536)
  if (i >= NHEADS * SEQ * SEQ) return;
  int h = i >> 16;
  int r = i & 65535;
  bf[i] = rpb[h * NBINS + idx[r]];
}

// ---------------- GEMM: C = A(M x 512) * B^T(N x 512) + bias ----------------
// Double-buffered (2 x 16 KB), counted vmcnt pipeline, chunk-swizzled LDS.
// EPI 0: scatter into q/k/v (B,H,N,D) bf16.  EPI 1: fp32 out row-major + bias.

__device__ __forceinline__ void stage_tile(const unsigned short* __restrict__ A,
                                           const unsigned short* __restrict__ Bw,
                                           char* gsm, int buf, int T,
                                           int m0, int n0, int t, int wv) {
  char* As = gsm + buf * 16384;
  char* Bs = As + 8192;
  const int kk = T * 32;
#pragma unroll
  for (int i = 0; i < 2; ++i) {
    int c = t + i * 256;               // LDS 16B-chunk id in [0,512)
    int row = c >> 2, ch = c & 3;
    int sch = ch ^ ((row >> 1) & 3);   // source swizzle (linear LDS dest)
    const unsigned short* ga = A + (size_t)(m0 + row) * 512 + kk + sch * 8;
    async16(ga, As + (i * 256 + wv * 64) * 16);
    const unsigned short* gb = Bw + (size_t)(n0 + row) * 512 + kk + sch * 8;
    async16(gb, Bs + (i * 256 + wv * 64) * 16);
  }
}

template<int EPI>
__global__ __launch_bounds__(256) void gemm_bt(
    const unsigned short* __restrict__ A,
    const unsigned short* __restrict__ Bw,
    const float* __restrict__ bias,
    void* __restrict__ outp) {
  __shared__ char gsm[32768];
  const int t = threadIdx.x;
  const int lane = t & 63;
  const int l15 = lane & 15, lg = lane >> 4;
  const int m0 = blockIdx.x * 128, n0 = blockIdx.y * 128;
  const int wv = t >> 6;
  const int wm = wv & 1, wn = wv >> 1;

  f32x4 acc[4][4];
  const f32x4 fz = {0.f, 0.f, 0.f, 0.f};
#pragma unroll
  for (int a = 0; a < 4; ++a)
#pragma unroll
    for (int b = 0; b < 4; ++b) acc[a][b] = fz;

  stage_tile(A, Bw, gsm, 0, 0, m0, n0, t, wv);
  stage_tile(A, Bw, gsm, 1, 1, m0, n0, t, wv);

#pragma unroll 2
  for (int T = 0; T < 16; ++T) {
    if (T < 15) asm volatile("s_waitcnt vmcnt(4)" ::: "memory");
    else        asm volatile("s_waitcnt vmcnt(0)" ::: "memory");
    __builtin_amdgcn_s_barrier();
    __builtin_amdgcn_sched_barrier(0);

    char* As = gsm + (T & 1) * 16384;
    char* Bs = As + 8192;
    bf16x8 af[4], bfr[4];
#pragma unroll
    for (int x = 0; x < 4; ++x) {
      int ra = wm * 64 + x * 16 + l15;
      af[x]  = *(const bf16x8*)(As + ra * 64 + ((lg ^ ((ra >> 1) & 3)) * 16));
      int rb = wn * 64 + x * 16 + l15;
      bfr[x] = *(const bf16x8*)(Bs + rb * 64 + ((lg ^ ((rb >> 1) & 3)) * 16));
    }
    asm volatile("s_waitcnt lgkmcnt(0)" ::: "memory");
    __builtin_amdgcn_sched_barrier(0);
    __builtin_amdgcn_s_barrier();

    if (T < 14) stage_tile(A, Bw, gsm, T & 1, T + 2, m0, n0, t, wv);
    __builtin_amdgcn_sched_barrier(0);

    __builtin_amdgcn_s_setprio(1);
#pragma unroll
    for (int mi = 0; mi < 4; ++mi)
#pragma unroll
      for (int ni = 0; ni < 4; ++ni)
        acc[mi][ni] = __builtin_amdgcn_mfma_f32_16x16x32_bf16(af[mi], bfr[ni], acc[mi][ni], 0, 0, 0);
    __builtin_amdgcn_s_setprio(0);
  }

#pragma unroll
  for (int mi = 0; mi < 4; ++mi)
#pragma unroll
    for (int ni = 0; ni < 4; ++ni)
#pragma unroll
      for (int r = 0; r < 4; ++r) {
        int row = m0 + wm * 64 + mi * 16 + lg * 4 + r;
        int col = n0 + wn * 64 + ni * 16 + l15;
        float v = acc[mi][ni][r] + bias[col];
        if (EPI == 0) {
          int which = col >> 9, hd = col & 511;
          int b = row >> 8, n = row & 255;
          ((unsigned short*)outp)[(size_t)which * BHND +
              (((size_t)(b * NHEADS + (hd >> 6)) * SEQ + n) * HDIM) + (hd & 63)] = f2bf(v);
        } else {
          ((float*)outp)[(size_t)row * 512 + col] = v;
        }
      }
}

// ---------------- fused attention: one block per (b,h) ----------------

__global__ __launch_bounds__(512, 2) void attn_kernel(
    const unsigned short* __restrict__ qb,
    const unsigned short* __restrict__ kb,
    const unsigned short* __restrict__ vb,
    const float* __restrict__ biasf,
    unsigned short* __restrict__ aout) {
  extern __shared__ char smem[];
  char* k_s = smem;               // 32 KB: [256 keys][64 d] bf16, XOR-swizzled rows
  char* v_s = smem + 32768;       // 32 KB: vT [64 d][256 keys] bf16, key+dhi swizzle
  const int t = threadIdx.x, lane = t & 63, w = t >> 6;
  const int l15 = lane & 15, lg = lane >> 4;
  char* P_s = smem + 65536 + w * 4096;  // per-wave [32 rows][64 keys] bf16, swizzled
  const int bh = blockIdx.x;
  const int h = bh & 7;
  const int b = bh >> 3;
  const size_t base = (size_t)bh * (SEQ * HDIM);

  // stage K (swizzled row-major)
#pragma unroll
  for (int i = 0; i < 4; ++i) {
    int c = i * 512 + t;            // 16B chunk, 2048 total
    int row = c >> 3, sl = c & 7;
    bf16x8 val = *(const bf16x8*)(kb + base + (size_t)c * 8);
    *(bf16x8*)(k_s + row * 128 + ((sl * 16) ^ ((row & 7) << 4))) = val;
  }
  // stage V transposed (vT[d][key]); swizzle spreads banks over key AND d>>3
#pragma unroll
  for (int i = 0; i < 4; ++i) {
    int c = i * 512 + t;
    int key = c >> 3, d0 = (c & 7) * 8;
    bf16x8 val = *(const bf16x8*)(vb + base + (size_t)c * 8);
#pragma unroll
    for (int j = 0; j < 8; ++j) {
      int d = d0 + j;
      int term = (((d & 7) ^ ((d >> 3) & 7)) << 4);
      *(short*)(v_s + d * 512 + ((key * 2) ^ term)) = val[j];
    }
  }
  // q fragments straight from global (L2-resident)
  bf16x8 qa[2][2];
#pragma unroll
  for (int rf = 0; rf < 2; ++rf)
#pragma unroll
    for (int ks = 0; ks < 2; ++ks)
      qa[rf][ks] = *(const bf16x8*)(qb + base + (size_t)(w * 32 + rf * 16 + l15) * 64 + ks * 32 + lg * 8);
  __syncthreads();

  // scores: S = q . k^T   (wave owns 32 query rows x 256 keys)
  f32x4 accs[2][16];
  const f32x4 fz = {0.f, 0.f, 0.f, 0.f};
#pragma unroll
  for (int a = 0; a < 2; ++a)
#pragma unroll
    for (int c = 0; c < 16; ++c) accs[a][c] = fz;
  __builtin_amdgcn_s_setprio(1);
#pragma unroll
  for (int cf = 0; cf < 16; ++cf) {
    int key = cf * 16 + l15;
#pragma unroll
    for (int ks = 0; ks < 2; ++ks) {
      bf16x8 kf = *(const bf16x8*)(k_s + key * 128 + ((lg * 16 + ks * 64) ^ ((key & 7) << 4)));
      accs[0][cf] = __builtin_amdgcn_mfma_f32_16x16x32_bf16(qa[0][ks], kf, accs[0][cf], 0, 0, 0);
      accs[1][cf] = __builtin_amdgcn_mfma_f32_16x16x32_bf16(qa[1][ks], kf, accs[1][cf], 0, 0, 0);
    }
  }
  __builtin_amdgcn_s_setprio(0);

  // scale + rel-pos bias
  const float* bh_ptr = biasf + h * 65536;
#pragma unroll
  for (int rf = 0; rf < 2; ++rf)
#pragma unroll
    for (int r = 0; r < 4; ++r) {
      int n = w * 32 + rf * 16 + lg * 4 + r;
      const float* bp = bh_ptr + n * 256 + l15;
#pragma unroll
      for (int cf = 0; cf < 16; ++cf)
        accs[rf][cf][r] = accs[rf][cf][r] * 0.125f + bp[cf * 16];
    }

  // softmax across 256 keys (16 in-lane x 16 lanes)
  float pinv[2][4];
#pragma unroll
  for (int rf = 0; rf < 2; ++rf)
#pragma unroll
    for (int r = 0; r < 4; ++r) {
      float m = -1e30f;
#pragma unroll
      for (int cf = 0; cf < 16; ++cf) m = fmaxf(m, accs[rf][cf][r]);
#pragma unroll
      for (int off = 1; off < 16; off <<= 1) m = fmaxf(m, __shfl_xor(m, off, 64));
      float s = 0.f;
#pragma unroll
      for (int cf = 0; cf < 16; ++cf) {
        float p = __expf(accs[rf][cf][r] - m);
        accs[rf][cf][r] = p;
        s += p;
      }
#pragma unroll
      for (int off = 1; off < 16; off <<= 1) s += __shfl_xor(s, off, 64);
      pinv[rf][r] = 1.0f / s;
    }

  // PV: out = P . V, P staged per-wave through LDS in 64-key chunks
  f32x4 acco[2][4];
#pragma unroll
  for (int a = 0; a < 2; ++a)
#pragma unroll
    for (int c2 = 0; c2 < 4; ++c2) acco[a][c2] = fz;

  for (int ch = 0; ch < 4; ++ch) {
#pragma unroll
    for (int rf = 0; rf < 2; ++rf)
#pragma unroll
      for (int cl = 0; cl < 4; ++cl)
#pragma unroll
        for (int r = 0; r < 4; ++r) {
          int rowl = rf * 16 + lg * 4 + r;
          int ml = cl * 16 + l15;
          float p = accs[rf][ch * 4 + cl][r] * pinv[rf][r];
          *(short*)(P_s + rowl * 128 + ((ml * 2) ^ ((rowl & 7) << 4))) = (short)f2bf(p);
        }
#pragma unroll
    for (int ks = 0; ks < 2; ++ks) {
      bf16x8 pa[2];
#pragma unroll
      for (int rf = 0; rf < 2; ++rf) {
        int row = rf * 16 + l15;
        pa[rf] = *(const bf16x8*)(P_s + row * 128 + ((lg * 16 + ks * 64) ^ ((row & 7) << 4)));
      }
      int keyb = (ch * 64 + ks * 32 + lg * 8) * 2;
      __builtin_amdgcn_s_setprio(1);
#pragma unroll
      for (int df = 0; df < 4; ++df) {
        int d = df * 16 + l15;
        int term = (((d & 7) ^ ((d >> 3) & 7)) << 4);
        bf16x8 vf = *(const bf16x8*)(v_s + d * 512 + (keyb ^ term));
        acco[0][df] = __builtin_amdgcn_mfma_f32_16x16x32_bf16(pa[0], vf, acco[0][df], 0, 0, 0);
        acco[1][df] = __builtin_amdgcn_mfma_f32_16x16x32_bf16(pa[1], vf, acco[1][df], 0, 0, 0);
      }
      __builtin_amdgcn_s_setprio(0);
    }
  }

  // write attn output in (b, n, h*64+d) bf16
#pragma unroll
  for (int rf = 0; rf < 2; ++rf)
#pragma unroll
    for (int df = 0; df < 4; ++df)
#pragma unroll
      for (int r = 0; r < 4; ++r) {
        int n = w * 32 + rf * 16 + lg * 4 + r;
        int d = df * 16 + l15;
        aout[((size_t)(b * SEQ + n)) * DIM + h * HDIM + d] = f2bf(acco[rf][df][r]);
      }
}

// ---------------- launch ----------------

extern "C" void kernel_launch(void* const* d_in, const int* in_sizes, int n_in,
                              void* d_out, int out_size, void* d_ws, size_t ws_size,
                              hipStream_t stream) {
  const float* x      = (const float*)d_in[0];
  const int*   rpi    = (const int*)d_in[1];
  const float* qkv_w  = (const float*)d_in[2];
  const float* qkv_b  = (const float*)d_in[3];
  const float* proj_w = (const float*)d_in[4];
  const float* proj_b = (const float*)d_in[5];
  const float* rpb    = (const float*)d_in[6];

  char* ws = (char*)d_ws;
  unsigned short* xb    = (unsigned short*)ws;                  // 16,777,216 B
  unsigned short* wqkv  = (unsigned short*)(ws + 16777216);     //  1,572,864 B
  unsigned short* wproj = (unsigned short*)(ws + 18350080);     //    524,288 B
  float*          biasf = (float*)         (ws + 18874368);     //  2,097,152 B
  unsigned short* qkvb  = (unsigned short*)(ws + 20971520);     // 50,331,648 B (q,k,v)
  unsigned short* aoutb = (unsigned short*)(ws + 71303168);     // 16,777,216 B
  // total ws use: 88,080,384 B

  cast_kernel<<<8192, 256, 0, stream>>>(x, xb, 2097152);
  cast_kernel<<<768, 256, 0, stream>>>(qkv_w, wqkv, 196608);
  cast_kernel<<<256, 256, 0, stream>>>(proj_w, wproj, 65536);
  bias_kernel<<<2048, 256, 0, stream>>>(rpi, rpb, biasf);

  dim3 g1(128, 12);
  gemm_bt<0><<<g1, 256, 0, stream>>>(xb, wqkv, qkv_b, (void*)qkvb);

  attn_kernel<<<512, 512, 98304, stream>>>(qkvb, qkvb + BHND, qkvb + 2 * (size_t)BHND,
                                           biasf, aoutb);

  dim3 g2(128, 4);
  gemm_bt<1><<<g2, 256, 0, stream>>>(aoutb, wproj, proj_b, d_out);
}